// Round 7
// baseline (100.678 us; speedup 1.0000x reference)
//
#include <hip/hip_runtime.h>
#include <hip/hip_bf16.h>
#include <stdint.h>

// ChebyKAN: y[b,o] = sum_{i,d} T_d(tanh(x[b,i])) * c[i,o,d]
//   == GEMM [16384 x 4096] x [4096 x 512]  (d=1..8; d=0 via column-sum)
// A generated on the fly (Chebyshev recurrence, 2 degrees per K-step);
// B pre-reordered to bf16 swizzled tiles in ws (4MB) + colsum f32 (2KB).
//
// R7: T4-lite. Double-buffered B tiles + raw s_barrier with counted
// s_waitcnt vmcnt(4) (never vmcnt(0) in the loop) — the per-step drain of
// freshly-issued global_load_lds was the exposed stall (both pipes ~30%).

#define BM 128
#define BN 128
#define BK 64              // 32 i-elems x 2 degrees
#define NSTEPS 64          // 16 i-tiles * 4 degree-pairs
#define IN_DIM 512
#define OUT_DIM 512

typedef __attribute__((ext_vector_type(8))) short short8;
typedef __attribute__((ext_vector_type(8))) unsigned short ushort8;
typedef __attribute__((ext_vector_type(4))) float f32x4;

__device__ __forceinline__ unsigned short f2bf(float f) {
  __hip_bfloat16 h = __float2bfloat16(f);
  return __builtin_bit_cast(unsigned short, h);
}

__device__ __forceinline__ float fast_tanh(float v) {
  float e = __expf(v + v);
  return 1.0f - 2.0f * __builtin_amdgcn_rcpf(e + 1.0f);
}

__device__ __forceinline__ void gload_lds16(const void* g, void* l) {
  __builtin_amdgcn_global_load_lds(
      (const __attribute__((address_space(1))) unsigned int*)(uintptr_t)g,
      (__attribute__((address_space(3))) unsigned int*)(uintptr_t)l,
      16, 0, 0);
}

// ---------------------------------------------------------------------------
// Kernel 1: coeffs[i][o][d] (f32) -> ws: bf16 B^T chunks, pre-swizzled.
// Chunk (nb, c) with c = itile*4 + p is a 16KB image of LDS tile
// [nl 0..127][128 B]: elem (il, dl) at byte nl*128 + ((dl*64+il*2)^((nl&7)<<4)),
// holding coeff d = 1 + 2p + dl.
// ---------------------------------------------------------------------------
__global__ __launch_bounds__(256) void cheby_reorder_b(
    const float* __restrict__ coeffs, unsigned char* __restrict__ bws) {
  const int g = blockIdx.x * 256 + threadIdx.x;  // 512*512 threads
  const int i = g & 511;
  const int o = g >> 9;
  const int nb = o >> 7, nl = o & 127;
  const int itile = i >> 5, il = i & 31;
  const float* cp = coeffs + (size_t)i * 4608 + (size_t)o * 9;
  const int swz = (nl & 7) << 4;
#pragma unroll
  for (int p = 0; p < 4; ++p) {
    const size_t base =
        ((size_t)(nb * 64 + itile * 4 + p) << 14) + (size_t)nl * 128;
    *(unsigned short*)(bws + base + ((il * 2) ^ swz)) = f2bf(cp[1 + 2 * p]);
    *(unsigned short*)(bws + base + ((64 + il * 2) ^ swz)) =
        f2bf(cp[2 + 2 * p]);
  }
}

// ---------------------------------------------------------------------------
// Kernel 2: colsum[o] = sum_i coeffs[i][o][0]   (T_0 == 1 contribution)
// ---------------------------------------------------------------------------
__global__ __launch_bounds__(64) void cheby_colsum(
    const float* __restrict__ coeffs, float* __restrict__ cs) {
  const int o = blockIdx.x;
  const int l = threadIdx.x;
  float s = 0.0f;
#pragma unroll
  for (int j = 0; j < 8; ++j)
    s += coeffs[(size_t)(l + j * 64) * 4608 + (size_t)o * 9];
#pragma unroll
  for (int off = 32; off > 0; off >>= 1) s += __shfl_down(s, off, 64);
  if (l == 0) cs[o] = s;
}

// ---------------------------------------------------------------------------
// Kernel 3: fused basis-gen + bf16 MFMA GEMM.
// 128x128 tile, BK=64, 4 waves (wave tile 64x64), 16x16x32 mfma, 4x4 frags.
// B double-buffered; counted-vmcnt raw barriers (no vmcnt(0) in loop).
// ---------------------------------------------------------------------------
__global__ __launch_bounds__(256, 3) void cheby_gemm(
    const float* __restrict__ x, const unsigned char* __restrict__ bws,
    const float* __restrict__ colsum, float* __restrict__ out) {
  const int bid = blockIdx.x;
  const int m0 = (bid >> 2) * BM;
  const int nblk = bid & 3;
  const int n0 = nblk * BN;
  const int tid = threadIdx.x;
  const int lane = tid & 63;
  const int wid = tid >> 6;          // 0..3
  const int wm = (wid >> 1) * 64;
  const int wn = (wid & 1) * 64;
  const int l15 = lane & 15;
  const int lhi = lane >> 4;

  __shared__ __align__(16) unsigned char As[BM * 128];      // 16KB swizzled
  __shared__ __align__(16) unsigned char Bs[2][BN * 128];   // 2x16KB swizzled

  // A staging: thread owns (srow = tid>>1, 16 i-elems at il = (tid&1)*16)
  const int srow = tid >> 1;
  const int ihalf = tid & 1;
  unsigned char* Arow = As + srow * 128;
  const int aswz = (srow & 7) << 4;
  const int wbase = ihalf * 32;      // byte offset of this thread's 16 elems

  float t2[16], Tm1[16], Tm2[16];
  f32x4 acc[4][4];
#pragma unroll
  for (int a = 0; a < 4; ++a)
#pragma unroll
    for (int b = 0; b < 4; ++b) acc[a][b] = (f32x4){0.f, 0.f, 0.f, 0.f};

  const unsigned char* bchunk0 = bws + ((size_t)(nblk * 64) << 14);
  const int goff = wid * 4096 + lane * 16;

  // ---- prologue: issue B(0) into Bs[0]
  {
    const unsigned char* gsrc = bchunk0 + goff;
    unsigned char* ldst = &Bs[0][0] + wid * 4096;
    gload_lds16(gsrc, ldst);
    gload_lds16(gsrc + 1024, ldst + 1024);
    gload_lds16(gsrc + 2048, ldst + 2048);
    gload_lds16(gsrc + 3072, ldst + 3072);
  }

  for (int s = 0; s < NSTEPS; ++s) {
    const int p = s & 1;

    // ---- issue B(s+1) into Bs[p^1] (last iter: dummy re-issue of 63)
    {
      const int snext = (s < NSTEPS - 1) ? s + 1 : NSTEPS - 1;
      const unsigned char* gsrc = bchunk0 + ((size_t)snext << 14) + goff;
      unsigned char* ldst = &Bs[p ^ 1][0] + wid * 4096;
      gload_lds16(gsrc, ldst);
      gload_lds16(gsrc + 1024, ldst + 1024);
      gload_lds16(gsrc + 2048, ldst + 2048);
      gload_lds16(gsrc + 3072, ldst + 3072);
    }

    // ---- A staging: advance recurrence 2 degrees; Tm2 = T_{d0}, Tm1 = T_{d1}
    const int q = s & 3;
    if (q == 0) {
      const int itile = s >> 2;
      const float* xp =
          x + (size_t)(m0 + srow) * IN_DIM + itile * 32 + ihalf * 16;
#pragma unroll
      for (int j = 0; j < 4; ++j) {
        const float4 v = reinterpret_cast<const float4*>(xp)[j];
        const float a0 = fast_tanh(v.x);
        const float a1 = fast_tanh(v.y);
        const float a2 = fast_tanh(v.z);
        const float a3 = fast_tanh(v.w);
        Tm2[4 * j + 0] = a0; Tm2[4 * j + 1] = a1;
        Tm2[4 * j + 2] = a2; Tm2[4 * j + 3] = a3;
        t2[4 * j + 0] = a0 + a0; t2[4 * j + 1] = a1 + a1;
        t2[4 * j + 2] = a2 + a2; t2[4 * j + 3] = a3 + a3;
        Tm1[4 * j + 0] = __builtin_fmaf(a0 + a0, a0, -1.0f);
        Tm1[4 * j + 1] = __builtin_fmaf(a1 + a1, a1, -1.0f);
        Tm1[4 * j + 2] = __builtin_fmaf(a2 + a2, a2, -1.0f);
        Tm1[4 * j + 3] = __builtin_fmaf(a3 + a3, a3, -1.0f);
      }
    } else {
#pragma unroll
      for (int e = 0; e < 16; ++e) {
        const float Ta = __builtin_fmaf(t2[e], Tm1[e], -Tm2[e]);
        const float Tb = __builtin_fmaf(t2[e], Ta, -Tm1[e]);
        Tm2[e] = Ta;
        Tm1[e] = Tb;
      }
    }
    // pack (T_{d0}, T_{d1}) to bf16; 4 swizzled ds_write_b128
    ushort8 pa0, pa1, pb0, pb1;
#pragma unroll
    for (int j = 0; j < 8; ++j) {
      pa0[j] = f2bf(Tm2[j]);
      pa1[j] = f2bf(Tm2[j + 8]);
      pb0[j] = f2bf(Tm1[j]);
      pb1[j] = f2bf(Tm1[j + 8]);
    }
    *(ushort8*)(Arow + ((wbase) ^ aswz)) = pa0;
    *(ushort8*)(Arow + ((wbase + 16) ^ aswz)) = pa1;
    *(ushort8*)(Arow + ((64 + wbase) ^ aswz)) = pb0;
    *(ushort8*)(Arow + ((64 + wbase + 16) ^ aswz)) = pb1;

    // ---- barrier 1: A written (lgkmcnt 0) + B(s) landed (vmcnt<=4 keeps
    // only the 4 just-issued B(s+1) loads in flight). Raw barrier: no drain.
    asm volatile("s_waitcnt vmcnt(4) lgkmcnt(0)" ::: "memory");
    __builtin_amdgcn_s_barrier();

    const unsigned char* Bcur = &Bs[p][0];
#pragma unroll
    for (int ks = 0; ks < 2; ++ks) {
      short8 af[4];
#pragma unroll
      for (int fm = 0; fm < 4; ++fm) {
        const int row = wm + fm * 16 + l15;
        af[fm] = *(const short8*)(
            As + row * 128 + ((ks * 64 + lhi * 16) ^ ((row & 7) << 4)));
      }
#pragma unroll
      for (int fn = 0; fn < 4; ++fn) {
        const int row = wn + fn * 16 + l15;
        const short8 bf = *(const short8*)(
            Bcur + row * 128 + ((ks * 64 + lhi * 16) ^ ((row & 7) << 4)));
#pragma unroll
        for (int fm = 0; fm < 4; ++fm)
          acc[fm][fn] = __builtin_amdgcn_mfma_f32_16x16x32_bf16(
              af[fm], bf, acc[fm][fn], 0, 0, 0);
      }
    }

    // ---- barrier 2: all reads of As/Bs[p] done before next iter overwrites.
    // Raw barrier: do NOT drain the in-flight B(s+1) loads.
    __builtin_amdgcn_s_barrier();
  }

  // ---- epilogue: add d=0 colsum, store f32
  float csv[4];
#pragma unroll
  for (int fn = 0; fn < 4; ++fn) csv[fn] = colsum[n0 + wn + fn * 16 + l15];
#pragma unroll
  for (int fm = 0; fm < 4; ++fm) {
    const int r0 = m0 + wm + fm * 16 + lhi * 4;
#pragma unroll
    for (int fn = 0; fn < 4; ++fn) {
      const int col = n0 + wn + fn * 16 + l15;
#pragma unroll
      for (int r = 0; r < 4; ++r)
        out[(size_t)(r0 + r) * OUT_DIM + col] = acc[fm][fn][r] + csv[fn];
    }
  }
}

extern "C" void kernel_launch(void* const* d_in, const int* in_sizes, int n_in,
                              void* d_out, int out_size, void* d_ws,
                              size_t ws_size, hipStream_t stream) {
  const float* x = (const float*)d_in[0];           // [16384, 512] f32
  const float* coeffs = (const float*)d_in[1];      // [512, 512, 9] f32
  float* out = (float*)d_out;                       // [16384, 512] f32
  unsigned char* bws = (unsigned char*)d_ws;        // 4MB bf16 B tiles
  float* cs = (float*)((unsigned char*)d_ws + ((size_t)4 << 20));  // +2KB

  hipLaunchKernelGGL(cheby_reorder_b, dim3(1024), dim3(256), 0, stream, coeffs,
                     bws);
  hipLaunchKernelGGL(cheby_colsum, dim3(512), dim3(64), 0, stream, coeffs, cs);
  hipLaunchKernelGGL(cheby_gemm, dim3(512), dim3(256), 0, stream, x, bws, cs,
                     out);
}